// Round 2
// baseline (102.129 us; speedup 1.0000x reference)
//
#include <hip/hip_runtime.h>
#include <math.h>

constexpr int kB   = 128;
constexpr int kP   = 2048;
constexpr int kRES = 4096;
constexpr int kF   = 256;
constexpr int kH   = 1024;
constexpr float kLN_EPS = 1e-5f;

__device__ __forceinline__ float gelu_exact(float x) {
    return 0.5f * x * (1.0f + erff(x * 0.70710678118654752f));
}

// Build proportional chain-start table cs[0..128] in LDS.
// Chain c handles batch b iff cs[b] <= c < cs[b+1]; counts ~ len[b]+K.
// K chosen so every batch gets >= 1 chain. Includes __syncthreads().
__device__ __forceinline__ void build_chain_starts(
    const int* __restrict__ plen, int C, int K, int tid,
    unsigned* s1, unsigned* s2, int* cs)
{
    if (tid < kB) s1[tid] = (unsigned)plen[tid] + (unsigned)K;
    __syncthreads();
    unsigned* src = s1; unsigned* dst = s2;
    #pragma unroll
    for (int d = 1; d < kB; d <<= 1) {
        if (tid < kB) dst[tid] = src[tid] + ((tid >= d) ? src[tid - d] : 0u);
        __syncthreads();
        unsigned* t = src; src = dst; dst = t;
    }
    const unsigned total = src[kB - 1];
    if (tid <= kB) {
        const unsigned pre = (tid == 0) ? 0u : src[tid - 1];
        cs[tid] = (int)(((unsigned long long)pre * (unsigned)C) / total);
    }
    __syncthreads();
}

// ---------------------------------------------------------------------------
// Kernel 1: balanced masked-row accumulation of g = GELU(LN(pd@W1+b1)).
// grid = C/4 blocks x 256. One wave = one chain; analytic LN (no per-row
// cross-lane reduce). Each chain owns a contiguous run of rows of one batch.
// ---------------------------------------------------------------------------
__global__ __launch_bounds__(256) void k1_pd_partial(
    const float* __restrict__ pd, const int* __restrict__ plen,
    const float* __restrict__ W1, const float* __restrict__ b1,
    const float* __restrict__ ln_g, const float* __restrict__ ln_b,
    float* __restrict__ partial, int C, int K)
{
    __shared__ unsigned s1[kB], s2[kB];
    __shared__ int cs[kB + 1];
    __shared__ float cons[14];
    __shared__ float pr[14][4];
    const int tid = threadIdx.x;

    // --- LN analytic constants: means of {w0,w1,w2,b, w0w0,w0w1,w0w2,w1w1,w1w2,w2w2, w0b,w1b,w2b,bb} ---
    {
        const float w0 = W1[tid], w1 = W1[256 + tid], w2 = W1[512 + tid], bb = b1[tid];
        float v[14] = { w0, w1, w2, bb, w0*w0, w0*w1, w0*w2, w1*w1, w1*w2, w2*w2,
                        w0*bb, w1*bb, w2*bb, bb*bb };
        #pragma unroll
        for (int off = 32; off; off >>= 1) {
            #pragma unroll
            for (int i = 0; i < 14; ++i) v[i] += __shfl_xor(v[i], off);
        }
        if ((tid & 63) == 0) {
            #pragma unroll
            for (int i = 0; i < 14; ++i) pr[i][tid >> 6] = v[i];
        }
    }
    build_chain_starts(plen, C, K, tid, s1, s2, cs);  // syncs cover pr too
    if (tid < 14)
        cons[tid] = (pr[tid][0] + pr[tid][1] + pr[tid][2] + pr[tid][3]) * (1.f / 256.f);
    __syncthreads();

    const int lane = tid & 63, wave = tid >> 6;
    const float4 w0q = ((const float4*)W1)[lane];
    const float4 w1q = ((const float4*)W1)[64 + lane];
    const float4 w2q = ((const float4*)W1)[128 + lane];
    const float4 bbq = ((const float4*)b1)[lane];
    const float4 ggq = ((const float4*)ln_g)[lane];
    const float4 beq = ((const float4*)ln_b)[lane];
    const float S0 = cons[0], S1c = cons[1], S2c = cons[2], Sb = cons[3];
    const float P00 = cons[4], P01 = cons[5], P02 = cons[6];
    const float P11 = cons[7], P12 = cons[8], P22 = cons[9];
    const float Q0 = cons[10], Q1 = cons[11], Q2 = cons[12], Rc = cons[13];

    const int c = blockIdx.x * 4 + wave;
    int lo = 0, hi = kB;
    while (hi - lo > 1) { const int mid = (lo + hi) >> 1; if (cs[mid] <= c) lo = mid; else hi = mid; }
    const int b = lo;
    const int m = cs[b + 1] - cs[b];
    const int j = c - cs[b];
    const int len = plen[b];
    const int q = len / m, r = len % m;
    const int start = j * q + min(j, r);
    const int cnt = q + ((j < r) ? 1 : 0);

    float a0 = 0.f, a1 = 0.f, a2 = 0.f, a3 = 0.f;
    const float* rp = pd + ((size_t)b * kP + start) * 3;
    #pragma unroll 2
    for (int it = 0; it < cnt; ++it, rp += 3) {
        const float x0 = rp[0], x1 = rp[1], x2 = rp[2];
        const float mu = fmaf(x2, S2c, fmaf(x1, S1c, fmaf(x0, S0, Sb)));
        const float sx = fmaf(P01 * x0, x1, fmaf(P02 * x0, x2, fmaf(P12 * x1, x2,
                         fmaf(Q0, x0, fmaf(Q1, x1, Q2 * x2)))));
        const float e2 = fmaf(P00 * x0, x0, fmaf(P11 * x1, x1, fmaf(P22 * x2, x2,
                         fmaf(2.f, sx, Rc))));
        const float rstd = rsqrtf(fmaf(-mu, mu, e2) + kLN_EPS);

        const float h0 = fmaf(x2, w2q.x, fmaf(x1, w1q.x, fmaf(x0, w0q.x, bbq.x)));
        const float h1 = fmaf(x2, w2q.y, fmaf(x1, w1q.y, fmaf(x0, w0q.y, bbq.y)));
        const float h2 = fmaf(x2, w2q.z, fmaf(x1, w1q.z, fmaf(x0, w0q.z, bbq.z)));
        const float h3 = fmaf(x2, w2q.w, fmaf(x1, w1q.w, fmaf(x0, w0q.w, bbq.w)));

        const float y0 = fmaf((h0 - mu) * rstd, ggq.x, beq.x);
        const float y1 = fmaf((h1 - mu) * rstd, ggq.y, beq.y);
        const float y2 = fmaf((h2 - mu) * rstd, ggq.z, beq.z);
        const float y3 = fmaf((h3 - mu) * rstd, ggq.w, beq.w);

        a0 += gelu_exact(y0);
        a1 += gelu_exact(y1);
        a2 += gelu_exact(y2);
        a3 += gelu_exact(y3);
    }
    ((float4*)(partial + ((size_t)c << 8)))[lane] = make_float4(a0, a1, a2, a3);
}

// ---------------------------------------------------------------------------
// Kernel 2: combined[b][1024] = concat(pd_pooled, betti_feat, pi_feat).
// grid = kB blocks x 256. Sums this batch's chain partials.
// ---------------------------------------------------------------------------
__global__ __launch_bounds__(256) void k2_combined(
    const float* __restrict__ partial, const int* __restrict__ plen,
    const float* __restrict__ W2, const float* __restrict__ b2,
    const int* __restrict__ betti, const float* __restrict__ betti_table,
    const float* __restrict__ pimg, const float* __restrict__ conv_w,
    const float* __restrict__ conv_b, float* __restrict__ combined, int C, int K)
{
    __shared__ unsigned s1[kB], s2[kB];
    __shared__ int cs[kB + 1];
    __shared__ float ml[256];
    __shared__ float sred[2][4];
    const int b    = blockIdx.x;
    const int tid  = threadIdx.x;
    const int wave = tid >> 6;
    const int lane = tid & 63;

    build_chain_starts(plen, C, K, tid, s1, s2, cs);

    // --- PI even/odd sums over 4096 elements ---
    const float4* x4 = (const float4*)(pimg + (size_t)b * kRES);
    float se = 0.f, so = 0.f;
    #pragma unroll
    for (int j = 0; j < 4; ++j) {
        const float4 v = x4[tid + j * 256];
        se += v.x + v.z;
        so += v.y + v.w;
    }
    #pragma unroll
    for (int off = 32; off; off >>= 1) {
        se += __shfl_xor(se, off);
        so += __shfl_xor(so, off);
    }
    if (lane == 0) { sred[0][wave] = se; sred[1][wave] = so; }

    // --- pooled mean over this batch's chains ---
    const int len = plen[b];
    const int c0 = cs[b], c1 = cs[b + 1];
    float sm = 0.f;
    for (int c = c0; c < c1; ++c) sm += partial[((size_t)c << 8) + tid];
    ml[tid] = (len > 0) ? sm / (float)len : 0.f;
    __syncthreads();

    se = (sred[0][0] + sred[0][1]) + (sred[0][2] + sred[0][3]);
    so = (sred[1][0] + sred[1][1]) + (sred[1][2] + sred[1][3]);

    // --- pd_pooled = mean_g @ W2 + b2 ---
    float acc = 0.f;
    #pragma unroll 4
    for (int f = 0; f < kF; ++f)
        acc = fmaf(ml[f], W2[(size_t)f * 256 + tid], acc);
    combined[(size_t)b * kH + tid] = (len > 0) ? (acc + b2[tid]) : 0.f;

    // --- betti ---
    const int i0 = min(max(betti[b * 3 + 0], 0), 9);
    const int i1 = min(max(betti[b * 3 + 1], 0), 9);
    const int i2 = min(max(betti[b * 3 + 2], 0), 9);
    combined[(size_t)b * kH + 256 + tid] =
        (betti_table[i0 * 256 + tid] + betti_table[i1 * 256 + tid] +
         betti_table[i2 * 256 + tid]) * (1.f / 3.f);

    // --- pi_feat: closed-form conv mean ---
    const float x0 = pimg[(size_t)b * kRES + 0];
    const float xe = pimg[(size_t)b * kRES + 4094];
    const float xo = pimg[(size_t)b * kRES + 4095];
    #pragma unroll
    for (int u = 0; u < 2; ++u) {
        const int c = tid + u * 256;
        const float* w = conv_w + (size_t)c * 5;
        const float v = w[0] * (se - xe) + w[1] * (so - xo) + w[2] * se +
                        w[3] * so + w[4] * (se - x0);
        combined[(size_t)b * kH + 512 + c] = v * (1.f / 2048.f) + conv_b[c];
    }
}

// ---------------------------------------------------------------------------
// Kernel 3a: split-K partial GEMM. grid (16 nt, 8 bt, 4 kt) x 256.
// Tile 16 batches x 64 cols x 256 K. LDS pad (65 f4/row) kills bank conflicts.
// ---------------------------------------------------------------------------
__global__ __launch_bounds__(256) void k3a_outproj(
    const float* __restrict__ combined, const float* __restrict__ Wo,
    float* __restrict__ kpart)
{
    const int nt  = blockIdx.x;
    const int bt  = blockIdx.y;
    const int kt  = blockIdx.z;
    const int tid = threadIdx.x;
    const int b0  = bt * 16;
    const int n0  = nt * 64;
    const int k0  = kt * 256;

    __shared__ float4 cl4[16 * 65];
    const float4* C4 = (const float4*)combined;
    #pragma unroll
    for (int j = 0; j < 4; ++j) {
        const int idx = j * 256 + tid;
        const int row = idx >> 6;
        const int cf  = idx & 63;
        cl4[row * 65 + cf] = C4[(size_t)(b0 + row) * 256 + (k0 >> 2) + cf];
    }
    __syncthreads();

    const int bl = tid >> 4;
    const int cg = tid & 15;
    const float4* Wo4 = (const float4*)Wo;
    const int wbase = (n0 >> 2) + cg;

    float4 acc = make_float4(0.f, 0.f, 0.f, 0.f);
    #pragma unroll 4
    for (int k4 = 0; k4 < 64; ++k4) {
        const float4 cv = cl4[bl * 65 + k4];
        const int k = k0 + k4 * 4;
        const float4 q0 = Wo4[(size_t)(k + 0) * 256 + wbase];
        const float4 q1 = Wo4[(size_t)(k + 1) * 256 + wbase];
        const float4 q2 = Wo4[(size_t)(k + 2) * 256 + wbase];
        const float4 q3 = Wo4[(size_t)(k + 3) * 256 + wbase];
        acc.x = fmaf(cv.x, q0.x, acc.x); acc.y = fmaf(cv.x, q0.y, acc.y);
        acc.z = fmaf(cv.x, q0.z, acc.z); acc.w = fmaf(cv.x, q0.w, acc.w);
        acc.x = fmaf(cv.y, q1.x, acc.x); acc.y = fmaf(cv.y, q1.y, acc.y);
        acc.z = fmaf(cv.y, q1.z, acc.z); acc.w = fmaf(cv.y, q1.w, acc.w);
        acc.x = fmaf(cv.z, q2.x, acc.x); acc.y = fmaf(cv.z, q2.y, acc.y);
        acc.z = fmaf(cv.z, q2.z, acc.z); acc.w = fmaf(cv.z, q2.w, acc.w);
        acc.x = fmaf(cv.w, q3.x, acc.x); acc.y = fmaf(cv.w, q3.y, acc.y);
        acc.z = fmaf(cv.w, q3.z, acc.z); acc.w = fmaf(cv.w, q3.w, acc.w);
    }
    ((float4*)kpart)[((size_t)(kt * kB + b0 + bl)) * 256 + wbase] = acc;
}

__global__ __launch_bounds__(256) void k3b_reduce(
    const float* __restrict__ kpart, const float* __restrict__ bo,
    float* __restrict__ out)
{
    const int g = blockIdx.x * 256 + threadIdx.x;   // float4 index over 128*256
    const float4* kp = (const float4*)kpart;
    float4 a = kp[g];
    #pragma unroll
    for (int t = 1; t < 4; ++t) {
        const float4 v = kp[(size_t)t * 32768 + g];
        a.x += v.x; a.y += v.y; a.z += v.z; a.w += v.w;
    }
    const float4 bq = ((const float4*)bo)[g & 255];
    a.x += bq.x; a.y += bq.y; a.z += bq.z; a.w += bq.w;
    ((float4*)out)[g] = a;
}

// Fallback fused k3 (small-ws path), same as round-0 version.
__global__ __launch_bounds__(256) void k3_fused(
    const float* __restrict__ combined, const float* __restrict__ Wo,
    const float* __restrict__ bo, float* __restrict__ out)
{
    const int nt  = blockIdx.x;
    const int bt  = blockIdx.y;
    const int tid = threadIdx.x;
    const int b0  = bt * 16;
    const int n0  = nt * 64;

    __shared__ float4 cl4[16 * 256];
    const float4* C4 = (const float4*)(combined + (size_t)b0 * kH);
    #pragma unroll
    for (int j = 0; j < 16; ++j)
        cl4[tid + j * 256] = C4[tid + j * 256];
    __syncthreads();

    const int bl = tid >> 4;
    const int cg = tid & 15;
    const float4* Wo4 = (const float4*)Wo;
    const int wbase = (n0 >> 2) + cg;

    float4 acc = make_float4(0.f, 0.f, 0.f, 0.f);
    for (int k4 = 0; k4 < 256; ++k4) {
        const float4 cv = cl4[bl * 256 + k4];
        const int k = k4 * 4;
        const float4 q0 = Wo4[(size_t)(k + 0) * 256 + wbase];
        const float4 q1 = Wo4[(size_t)(k + 1) * 256 + wbase];
        const float4 q2 = Wo4[(size_t)(k + 2) * 256 + wbase];
        const float4 q3 = Wo4[(size_t)(k + 3) * 256 + wbase];
        acc.x = fmaf(cv.x, q0.x, acc.x); acc.y = fmaf(cv.x, q0.y, acc.y);
        acc.z = fmaf(cv.x, q0.z, acc.z); acc.w = fmaf(cv.x, q0.w, acc.w);
        acc.x = fmaf(cv.y, q1.x, acc.x); acc.y = fmaf(cv.y, q1.y, acc.y);
        acc.z = fmaf(cv.y, q1.z, acc.z); acc.w = fmaf(cv.y, q1.w, acc.w);
        acc.x = fmaf(cv.z, q2.x, acc.x); acc.y = fmaf(cv.z, q2.y, acc.y);
        acc.z = fmaf(cv.z, q2.z, acc.z); acc.w = fmaf(cv.z, q2.w, acc.w);
        acc.x = fmaf(cv.w, q3.x, acc.x); acc.y = fmaf(cv.w, q3.y, acc.y);
        acc.z = fmaf(cv.w, q3.z, acc.z); acc.w = fmaf(cv.w, q3.w, acc.w);
    }
    const float4 bv = ((const float4*)bo)[wbase];
    float4 r;
    r.x = acc.x + bv.x; r.y = acc.y + bv.y;
    r.z = acc.z + bv.z; r.w = acc.w + bv.w;
    ((float4*)(out + (size_t)(b0 + bl) * kH + n0))[cg] = r;
}

// ---------------------------------------------------------------------------
extern "C" void kernel_launch(void* const* d_in, const int* in_sizes, int n_in,
                              void* d_out, int out_size, void* d_ws, size_t ws_size,
                              hipStream_t stream) {
    const float* pd   = (const float*)d_in[0];
    const int*   plen = (const int*)  d_in[1];
    const int*   bnum = (const int*)  d_in[2];
    const float* pimg = (const float*)d_in[3];
    const float* W1   = (const float*)d_in[4];
    const float* b1   = (const float*)d_in[5];
    const float* lng  = (const float*)d_in[6];
    const float* lnb  = (const float*)d_in[7];
    const float* W2   = (const float*)d_in[8];
    const float* b2   = (const float*)d_in[9];
    const float* btab = (const float*)d_in[10];
    const float* cw   = (const float*)d_in[11];
    const float* cb   = (const float*)d_in[12];
    const float* Wo   = (const float*)d_in[13];
    const float* bo   = (const float*)d_in[14];
    float* out = (float*)d_out;

    // Pick chain count C and k3 split by available workspace.
    const int Cs[4]  = {8192, 4096, 2048, 2048};
    const int KTs[4] = {4, 4, 4, 1};
    int C = 2048, KT = 1;
    for (int i = 0; i < 4; ++i) {
        const size_t need = (size_t)Cs[i] * 256 * 4 + (size_t)kB * kH * 4 +
                            (KTs[i] == 4 ? (size_t)4 * kB * kH * 4 : 0);
        if (ws_size >= need) { C = Cs[i]; KT = KTs[i]; break; }
    }
    const int K = (kB * kP + C - 129) / (C - 128);   // guarantees >=1 chain/batch

    float* partial  = (float*)d_ws;                   // C*256 floats
    float* combined = partial + (size_t)C * 256;      // 128*1024 floats
    float* kpart    = combined + (size_t)kB * kH;     // 4*128*1024 floats (if KT==4)

    k1_pd_partial<<<dim3(C / 4), 256, 0, stream>>>(pd, plen, W1, b1, lng, lnb, partial, C, K);
    k2_combined<<<dim3(kB), 256, 0, stream>>>(partial, plen, W2, b2, bnum, btab, pimg, cw, cb,
                                              combined, C, K);
    if (KT == 4) {
        k3a_outproj<<<dim3(16, 8, 4), 256, 0, stream>>>(combined, Wo, kpart);
        k3b_reduce<<<dim3(kB), 256, 0, stream>>>(kpart, bo, out);
    } else {
        k3_fused<<<dim3(16, 8), 256, 0, stream>>>(combined, Wo, bo, out);
    }
}

// Round 4
// 93.222 us; speedup vs baseline: 1.0956x; 1.0956x over previous
//
#include <hip/hip_runtime.h>
#include <math.h>

constexpr int kB   = 128;
constexpr int kP   = 2048;
constexpr int kRES = 4096;
constexpr int kF   = 256;
constexpr int kH   = 1024;
constexpr float kLN_EPS = 1e-5f;

#if __has_builtin(__builtin_amdgcn_exp2f)
#define EXP2F __builtin_amdgcn_exp2f
#else
#define EXP2F exp2f
#endif
#if __has_builtin(__builtin_amdgcn_rcpf)
#define RCPF __builtin_amdgcn_rcpf
#else
#define RCPF(x) (1.0f / (x))
#endif

// gelu(y) = 0.5*y*(1+erf(y/sqrt2)); erf via A&S 7.1.25 (3-term, |err|<=2.5e-5),
// 0.5 and 1/sqrt2 folded into constants. ~13 VALU slots, 1 rcp + 1 exp.
__device__ __forceinline__ float gelu_fast(float y) {
    const float a = fabsf(y);
    const float t = RCPF(fmaf(0.33267096f, a, 1.0f));       // 1/(1 + p*a/sqrt2)
    const float e = EXP2F(-0.72134752f * y * y);            // exp(-y^2/2)
    const float p = fmaf(fmaf(0.37392780f, t, -0.04793990f), t, 0.17401210f);
    const float w = (p * t) * e;                            // 0.5*erfc(a/sqrt2)
    return fmaf(-a, w, fmaf(0.5f, y, 0.5f * a));
}

// Build proportional chain-start table cs[0..128] in LDS.
// Chain c handles batch b iff cs[b] <= c < cs[b+1]; counts ~ len[b]+K.
// K chosen so every batch gets >= 1 chain. Includes __syncthreads().
__device__ __forceinline__ void build_chain_starts(
    const int* __restrict__ plen, int C, int K, int tid,
    unsigned* s1, unsigned* s2, int* cs)
{
    if (tid < kB) s1[tid] = (unsigned)plen[tid] + (unsigned)K;
    __syncthreads();
    unsigned* src = s1; unsigned* dst = s2;
    #pragma unroll
    for (int d = 1; d < kB; d <<= 1) {
        if (tid < kB) dst[tid] = src[tid] + ((tid >= d) ? src[tid - d] : 0u);
        __syncthreads();
        unsigned* t = src; src = dst; dst = t;
    }
    const unsigned total = src[kB - 1];
    if (tid <= kB) {
        const unsigned pre = (tid == 0) ? 0u : src[tid - 1];
        cs[tid] = (int)(((unsigned long long)pre * (unsigned)C) / total);
    }
    __syncthreads();
}

// ---------------------------------------------------------------------------
// Kernel 1: balanced masked-row accumulation of g = GELU(LN(pd@W1+b1)).
// grid = C/4 blocks x 256. One wave = one chain; analytic LN (no per-row
// cross-lane reduce). Each chain owns a contiguous run of rows of one batch.
// ---------------------------------------------------------------------------
__global__ __launch_bounds__(256) void k1_pd_partial(
    const float* __restrict__ pd, const int* __restrict__ plen,
    const float* __restrict__ W1, const float* __restrict__ b1,
    const float* __restrict__ ln_g, const float* __restrict__ ln_b,
    float* __restrict__ partial, int C, int K)
{
    __shared__ unsigned s1[kB], s2[kB];
    __shared__ int cs[kB + 1];
    __shared__ float cons[14];
    __shared__ float pr[14][4];
    const int tid = threadIdx.x;

    // --- LN analytic constants: means of {w0,w1,w2,b, w0w0,w0w1,w0w2,w1w1,w1w2,w2w2, w0b,w1b,w2b,bb} ---
    {
        const float w0 = W1[tid], w1 = W1[256 + tid], w2 = W1[512 + tid], bb = b1[tid];
        float v[14] = { w0, w1, w2, bb, w0*w0, w0*w1, w0*w2, w1*w1, w1*w2, w2*w2,
                        w0*bb, w1*bb, w2*bb, bb*bb };
        #pragma unroll
        for (int off = 32; off; off >>= 1) {
            #pragma unroll
            for (int i = 0; i < 14; ++i) v[i] += __shfl_xor(v[i], off);
        }
        if ((tid & 63) == 0) {
            #pragma unroll
            for (int i = 0; i < 14; ++i) pr[i][tid >> 6] = v[i];
        }
    }
    build_chain_starts(plen, C, K, tid, s1, s2, cs);  // syncs cover pr too
    if (tid < 14)
        cons[tid] = (pr[tid][0] + pr[tid][1] + pr[tid][2] + pr[tid][3]) * (1.f / 256.f);
    __syncthreads();

    const int lane = tid & 63, wave = tid >> 6;
    const float4 w0q = ((const float4*)W1)[lane];
    const float4 w1q = ((const float4*)W1)[64 + lane];
    const float4 w2q = ((const float4*)W1)[128 + lane];
    const float4 bbq = ((const float4*)b1)[lane];
    const float4 ggq = ((const float4*)ln_g)[lane];
    const float4 beq = ((const float4*)ln_b)[lane];
    const float S0 = cons[0], S1c = cons[1], S2c = cons[2], Sb = cons[3];
    const float P00 = cons[4], P01 = cons[5], P02 = cons[6];
    const float P11 = cons[7], P12 = cons[8], P22 = cons[9];
    const float Q0 = cons[10], Q1 = cons[11], Q2 = cons[12], Rc = cons[13];

    const int c = blockIdx.x * 4 + wave;
    int lo = 0, hi = kB;
    while (hi - lo > 1) { const int mid = (lo + hi) >> 1; if (cs[mid] <= c) lo = mid; else hi = mid; }
    const int b = lo;
    const int m = cs[b + 1] - cs[b];
    const int j = c - cs[b];
    const int len = plen[b];
    const int q = len / m, r = len % m;
    const int start = j * q + min(j, r);
    const int cnt = q + ((j < r) ? 1 : 0);

    float a0 = 0.f, a1 = 0.f, a2 = 0.f, a3 = 0.f;
    const float* rp = pd + ((size_t)b * kP + start) * 3;
    #pragma unroll 2
    for (int it = 0; it < cnt; ++it, rp += 3) {
        const float x0 = rp[0], x1 = rp[1], x2 = rp[2];
        const float mu = fmaf(x2, S2c, fmaf(x1, S1c, fmaf(x0, S0, Sb)));
        const float sx = fmaf(P01 * x0, x1, fmaf(P02 * x0, x2, fmaf(P12 * x1, x2,
                         fmaf(Q0, x0, fmaf(Q1, x1, Q2 * x2)))));
        const float e2 = fmaf(P00 * x0, x0, fmaf(P11 * x1, x1, fmaf(P22 * x2, x2,
                         fmaf(2.f, sx, Rc))));
        const float rstd = rsqrtf(fmaf(-mu, mu, e2) + kLN_EPS);

        const float h0 = fmaf(x2, w2q.x, fmaf(x1, w1q.x, fmaf(x0, w0q.x, bbq.x)));
        const float h1 = fmaf(x2, w2q.y, fmaf(x1, w1q.y, fmaf(x0, w0q.y, bbq.y)));
        const float h2 = fmaf(x2, w2q.z, fmaf(x1, w1q.z, fmaf(x0, w0q.z, bbq.z)));
        const float h3 = fmaf(x2, w2q.w, fmaf(x1, w1q.w, fmaf(x0, w0q.w, bbq.w)));

        const float y0 = fmaf((h0 - mu) * rstd, ggq.x, beq.x);
        const float y1 = fmaf((h1 - mu) * rstd, ggq.y, beq.y);
        const float y2 = fmaf((h2 - mu) * rstd, ggq.z, beq.z);
        const float y3 = fmaf((h3 - mu) * rstd, ggq.w, beq.w);

        a0 += gelu_fast(y0);
        a1 += gelu_fast(y1);
        a2 += gelu_fast(y2);
        a3 += gelu_fast(y3);
    }
    ((float4*)(partial + ((size_t)c << 8)))[lane] = make_float4(a0, a1, a2, a3);
}

// ---------------------------------------------------------------------------
// Kernel 2: combined[b][1024] = concat(pd_pooled, betti_feat, pi_feat).
// grid = kB blocks x 256. Sums this batch's chain partials. (round-2 verbatim)
// ---------------------------------------------------------------------------
__global__ __launch_bounds__(256) void k2_combined(
    const float* __restrict__ partial, const int* __restrict__ plen,
    const float* __restrict__ W2, const float* __restrict__ b2,
    const int* __restrict__ betti, const float* __restrict__ betti_table,
    const float* __restrict__ pimg, const float* __restrict__ conv_w,
    const float* __restrict__ conv_b, float* __restrict__ combined, int C, int K)
{
    __shared__ unsigned s1[kB], s2[kB];
    __shared__ int cs[kB + 1];
    __shared__ float ml[256];
    __shared__ float sred[2][4];
    const int b    = blockIdx.x;
    const int tid  = threadIdx.x;
    const int wave = tid >> 6;
    const int lane = tid & 63;

    build_chain_starts(plen, C, K, tid, s1, s2, cs);

    // --- PI even/odd sums over 4096 elements ---
    const float4* x4 = (const float4*)(pimg + (size_t)b * kRES);
    float se = 0.f, so = 0.f;
    #pragma unroll
    for (int j = 0; j < 4; ++j) {
        const float4 v = x4[tid + j * 256];
        se += v.x + v.z;
        so += v.y + v.w;
    }
    #pragma unroll
    for (int off = 32; off; off >>= 1) {
        se += __shfl_xor(se, off);
        so += __shfl_xor(so, off);
    }
    if (lane == 0) { sred[0][wave] = se; sred[1][wave] = so; }

    // --- pooled mean over this batch's chains ---
    const int len = plen[b];
    const int c0 = cs[b], c1 = cs[b + 1];
    float sm = 0.f;
    for (int c = c0; c < c1; ++c) sm += partial[((size_t)c << 8) + tid];
    ml[tid] = (len > 0) ? sm / (float)len : 0.f;
    __syncthreads();

    se = (sred[0][0] + sred[0][1]) + (sred[0][2] + sred[0][3]);
    so = (sred[1][0] + sred[1][1]) + (sred[1][2] + sred[1][3]);

    // --- pd_pooled = mean_g @ W2 + b2 ---
    float acc = 0.f;
    #pragma unroll 4
    for (int f = 0; f < kF; ++f)
        acc = fmaf(ml[f], W2[(size_t)f * 256 + tid], acc);
    combined[(size_t)b * kH + tid] = (len > 0) ? (acc + b2[tid]) : 0.f;

    // --- betti ---
    const int i0 = min(max(betti[b * 3 + 0], 0), 9);
    const int i1 = min(max(betti[b * 3 + 1], 0), 9);
    const int i2 = min(max(betti[b * 3 + 2], 0), 9);
    combined[(size_t)b * kH + 256 + tid] =
        (betti_table[i0 * 256 + tid] + betti_table[i1 * 256 + tid] +
         betti_table[i2 * 256 + tid]) * (1.f / 3.f);

    // --- pi_feat: closed-form conv mean ---
    const float x0 = pimg[(size_t)b * kRES + 0];
    const float xe = pimg[(size_t)b * kRES + 4094];
    const float xo = pimg[(size_t)b * kRES + 4095];
    #pragma unroll
    for (int u = 0; u < 2; ++u) {
        const int c = tid + u * 256;
        const float* w = conv_w + (size_t)c * 5;
        const float v = w[0] * (se - xe) + w[1] * (so - xo) + w[2] * se +
                        w[3] * so + w[4] * (se - x0);
        combined[(size_t)b * kH + 512 + c] = v * (1.f / 2048.f) + conv_b[c];
    }
}

// ---------------------------------------------------------------------------
// Kernel 3a: split-K partial GEMM. grid (16 nt, 8 bt, 4 kt) x 256.
// Tile 16 batches x 64 cols x 256 K. LDS pad (65 f4/row). (round-2 verbatim)
// ---------------------------------------------------------------------------
__global__ __launch_bounds__(256) void k3a_outproj(
    const float* __restrict__ combined, const float* __restrict__ Wo,
    float* __restrict__ kpart)
{
    const int nt  = blockIdx.x;
    const int bt  = blockIdx.y;
    const int kt  = blockIdx.z;
    const int tid = threadIdx.x;
    const int b0  = bt * 16;
    const int n0  = nt * 64;
    const int k0  = kt * 256;

    __shared__ float4 cl4[16 * 65];
    const float4* C4 = (const float4*)combined;
    #pragma unroll
    for (int j = 0; j < 4; ++j) {
        const int idx = j * 256 + tid;
        const int row = idx >> 6;
        const int cf  = idx & 63;
        cl4[row * 65 + cf] = C4[(size_t)(b0 + row) * 256 + (k0 >> 2) + cf];
    }
    __syncthreads();

    const int bl = tid >> 4;
    const int cg = tid & 15;
    const float4* Wo4 = (const float4*)Wo;
    const int wbase = (n0 >> 2) + cg;

    float4 acc = make_float4(0.f, 0.f, 0.f, 0.f);
    #pragma unroll 4
    for (int k4 = 0; k4 < 64; ++k4) {
        const float4 cv = cl4[bl * 65 + k4];
        const int k = k0 + k4 * 4;
        const float4 q0 = Wo4[(size_t)(k + 0) * 256 + wbase];
        const float4 q1 = Wo4[(size_t)(k + 1) * 256 + wbase];
        const float4 q2 = Wo4[(size_t)(k + 2) * 256 + wbase];
        const float4 q3 = Wo4[(size_t)(k + 3) * 256 + wbase];
        acc.x = fmaf(cv.x, q0.x, acc.x); acc.y = fmaf(cv.x, q0.y, acc.y);
        acc.z = fmaf(cv.x, q0.z, acc.z); acc.w = fmaf(cv.x, q0.w, acc.w);
        acc.x = fmaf(cv.y, q1.x, acc.x); acc.y = fmaf(cv.y, q1.y, acc.y);
        acc.z = fmaf(cv.y, q1.z, acc.z); acc.w = fmaf(cv.y, q1.w, acc.w);
        acc.x = fmaf(cv.z, q2.x, acc.x); acc.y = fmaf(cv.z, q2.y, acc.y);
        acc.z = fmaf(cv.z, q2.z, acc.z); acc.w = fmaf(cv.z, q2.w, acc.w);
        acc.x = fmaf(cv.w, q3.x, acc.x); acc.y = fmaf(cv.w, q3.y, acc.y);
        acc.z = fmaf(cv.w, q3.z, acc.z); acc.w = fmaf(cv.w, q3.w, acc.w);
    }
    ((float4*)kpart)[((size_t)(kt * kB + b0 + bl)) * 256 + wbase] = acc;
}

__global__ __launch_bounds__(256) void k3b_reduce(
    const float* __restrict__ kpart, const float* __restrict__ bo,
    float* __restrict__ out)
{
    const int g = blockIdx.x * 256 + threadIdx.x;   // float4 index over 128*256
    const float4* kp = (const float4*)kpart;
    float4 a = kp[g];
    #pragma unroll
    for (int t = 1; t < 4; ++t) {
        const float4 v = kp[(size_t)t * 32768 + g];
        a.x += v.x; a.y += v.y; a.z += v.z; a.w += v.w;
    }
    const float4 bq = ((const float4*)bo)[g & 255];
    a.x += bq.x; a.y += bq.y; a.z += bq.z; a.w += bq.w;
    ((float4*)out)[g] = a;
}

// Fallback fused k3 (small-ws path), round-2 verbatim.
__global__ __launch_bounds__(256) void k3_fused(
    const float* __restrict__ combined, const float* __restrict__ Wo,
    const float* __restrict__ bo, float* __restrict__ out)
{
    const int nt  = blockIdx.x;
    const int bt  = blockIdx.y;
    const int tid = threadIdx.x;
    const int b0  = bt * 16;
    const int n0  = nt * 64;

    __shared__ float4 cl4[16 * 256];
    const float4* C4 = (const float4*)(combined + (size_t)b0 * kH);
    #pragma unroll
    for (int j = 0; j < 16; ++j)
        cl4[tid + j * 256] = C4[tid + j * 256];
    __syncthreads();

    const int bl = tid >> 4;
    const int cg = tid & 15;
    const float4* Wo4 = (const float4*)Wo;
    const int wbase = (n0 >> 2) + cg;

    float4 acc = make_float4(0.f, 0.f, 0.f, 0.f);
    for (int k4 = 0; k4 < 256; ++k4) {
        const float4 cv = cl4[bl * 256 + k4];
        const int k = k4 * 4;
        const float4 q0 = Wo4[(size_t)(k + 0) * 256 + wbase];
        const float4 q1 = Wo4[(size_t)(k + 1) * 256 + wbase];
        const float4 q2 = Wo4[(size_t)(k + 2) * 256 + wbase];
        const float4 q3 = Wo4[(size_t)(k + 3) * 256 + wbase];
        acc.x = fmaf(cv.x, q0.x, acc.x); acc.y = fmaf(cv.x, q0.y, acc.y);
        acc.z = fmaf(cv.x, q0.z, acc.z); acc.w = fmaf(cv.x, q0.w, acc.w);
        acc.x = fmaf(cv.y, q1.x, acc.x); acc.y = fmaf(cv.y, q1.y, acc.y);
        acc.z = fmaf(cv.y, q1.z, acc.z); acc.w = fmaf(cv.y, q1.w, acc.w);
        acc.x = fmaf(cv.z, q2.x, acc.x); acc.y = fmaf(cv.z, q2.y, acc.y);
        acc.z = fmaf(cv.z, q2.z, acc.z); acc.w = fmaf(cv.z, q2.w, acc.w);
        acc.x = fmaf(cv.w, q3.x, acc.x); acc.y = fmaf(cv.w, q3.y, acc.y);
        acc.z = fmaf(cv.w, q3.z, acc.z); acc.w = fmaf(cv.w, q3.w, acc.w);
    }
    const float4 bv = ((const float4*)bo)[wbase];
    float4 r;
    r.x = acc.x + bv.x; r.y = acc.y + bv.y;
    r.z = acc.z + bv.z; r.w = acc.w + bv.w;
    ((float4*)(out + (size_t)(b0 + bl) * kH + n0))[cg] = r;
}

// ---------------------------------------------------------------------------
extern "C" void kernel_launch(void* const* d_in, const int* in_sizes, int n_in,
                              void* d_out, int out_size, void* d_ws, size_t ws_size,
                              hipStream_t stream) {
    const float* pd   = (const float*)d_in[0];
    const int*   plen = (const int*)  d_in[1];
    const int*   bnum = (const int*)  d_in[2];
    const float* pimg = (const float*)d_in[3];
    const float* W1   = (const float*)d_in[4];
    const float* b1   = (const float*)d_in[5];
    const float* lng  = (const float*)d_in[6];
    const float* lnb  = (const float*)d_in[7];
    const float* W2   = (const float*)d_in[8];
    const float* b2   = (const float*)d_in[9];
    const float* btab = (const float*)d_in[10];
    const float* cw   = (const float*)d_in[11];
    const float* cb   = (const float*)d_in[12];
    const float* Wo   = (const float*)d_in[13];
    const float* bo   = (const float*)d_in[14];
    float* out = (float*)d_out;

    // Pick chain count C and k3 split by available workspace (round-2 verbatim).
    const int Cs[4]  = {8192, 4096, 2048, 2048};
    const int KTs[4] = {4, 4, 4, 1};
    int C = 2048, KT = 1;
    for (int i = 0; i < 4; ++i) {
        const size_t need = (size_t)Cs[i] * 256 * 4 + (size_t)kB * kH * 4 +
                            (KTs[i] == 4 ? (size_t)4 * kB * kH * 4 : 0);
        if (ws_size >= need) { C = Cs[i]; KT = KTs[i]; break; }
    }
    const int K = (kB * kP + C - 129) / (C - 128);   // guarantees >=1 chain/batch

    float* partial  = (float*)d_ws;                   // C*256 floats
    float* combined = partial + (size_t)C * 256;      // 128*1024 floats
    float* kpart    = combined + (size_t)kB * kH;     // 4*128*1024 floats (if KT==4)

    k1_pd_partial<<<dim3(C / 4), 256, 0, stream>>>(pd, plen, W1, b1, lng, lnb, partial, C, K);
    k2_combined<<<dim3(kB), 256, 0, stream>>>(partial, plen, W2, b2, bnum, btab, pimg, cw, cb,
                                              combined, C, K);
    if (KT == 4) {
        k3a_outproj<<<dim3(16, 8, 4), 256, 0, stream>>>(combined, Wo, kpart);
        k3b_reduce<<<dim3(kB), 256, 0, stream>>>(kpart, bo, out);
    } else {
        k3_fused<<<dim3(16, 8), 256, 0, stream>>>(combined, Wo, bo, out);
    }
}